// Round 1
// baseline (841.412 us; speedup 1.0000x reference)
//
#include <hip/hip_runtime.h>

#define BB 32
#define NN 512
#define HH 512
constexpr float QK_SCALE = 0.04419417382415922f; // 1/sqrt(512)

using bf16x8 = __attribute__((ext_vector_type(8))) short;
using f32x4  = __attribute__((ext_vector_type(4))) float;
typedef unsigned int u32;

// fp32 -> bf16 round-to-nearest-even (inputs are finite; no NaN path needed)
__device__ __forceinline__ short f2bf(float f) {
  unsigned int u = __float_as_uint(f);
  unsigned int r = (u + 0x7FFFu + ((u >> 16) & 1u)) >> 16;
  return (short)r;
}

// async global->LDS 16B copy. LDS dest must be wave-uniform base + lane*16,
// which our staging index (linear in thread id) guarantees.
__device__ __forceinline__ void gl_lds16(const short* g, short* l) {
  __builtin_amdgcn_global_load_lds(
      (const __attribute__((address_space(1))) u32*)g,
      (__attribute__((address_space(3))) u32*)l, 16, 0, 0);
}

// ---------------------------------------------------------------------------
// prep_x: x fp32 [B][N][H] -> xbf bf16 (same layout) and xT bf16 [B][H][N]
// ---------------------------------------------------------------------------
__global__ __launch_bounds__(256) void prep_x(const float* __restrict__ x,
                                              short* __restrict__ xbf,
                                              short* __restrict__ xT) {
  __shared__ float tile[32][33];
  const int b = blockIdx.z;
  const int n0 = blockIdx.y * 32, h0 = blockIdx.x * 32;
  const int t = threadIdx.x;
  const int i = t >> 3;          // 0..31
  const int j4 = (t & 7) * 4;    // 0,4,...,28
  const float4 v = *(const float4*)&x[((long)b * NN + n0 + i) * HH + h0 + j4];
  short o[4] = {f2bf(v.x), f2bf(v.y), f2bf(v.z), f2bf(v.w)};
  *(uint2*)&xbf[((long)b * NN + n0 + i) * HH + h0 + j4] = *(uint2*)o;
  tile[i][j4 + 0] = v.x; tile[i][j4 + 1] = v.y;
  tile[i][j4 + 2] = v.z; tile[i][j4 + 3] = v.w;
  __syncthreads();
  short p[4] = {f2bf(tile[j4 + 0][i]), f2bf(tile[j4 + 1][i]),
                f2bf(tile[j4 + 2][i]), f2bf(tile[j4 + 3][i])};
  *(uint2*)&xT[((long)b * HH + h0 + i) * NN + n0 + j4] = *(uint2*)p;
}

// ---------------------------------------------------------------------------
// prep_w: Wq/Wk fp32 [H][D] -> Wqt/Wkt bf16 [D][H]  (blockIdx.z selects q/k)
// ---------------------------------------------------------------------------
__global__ __launch_bounds__(256) void prep_w(const float* __restrict__ Wq,
                                              const float* __restrict__ Wk,
                                              short* __restrict__ Wqt,
                                              short* __restrict__ Wkt) {
  __shared__ float tile[32][33];
  const float* W = blockIdx.z ? Wk : Wq;
  short* Wt = blockIdx.z ? Wkt : Wqt;
  const int h0 = blockIdx.y * 32, d0 = blockIdx.x * 32;
  const int t = threadIdx.x;
  const int i = t >> 3;
  const int j4 = (t & 7) * 4;
  const float4 v = *(const float4*)&W[(long)(h0 + i) * HH + d0 + j4];
  tile[i][j4 + 0] = v.x; tile[i][j4 + 1] = v.y;
  tile[i][j4 + 2] = v.z; tile[i][j4 + 3] = v.w;
  __syncthreads();
  short p[4] = {f2bf(tile[j4 + 0][i]), f2bf(tile[j4 + 1][i]),
                f2bf(tile[j4 + 2][i]), f2bf(tile[j4 + 3][i])};
  *(uint2*)&Wt[(long)(d0 + i) * HH + h0 + j4] = *(uint2*)p;
}

// ---------------------------------------------------------------------------
// gemm128: m97-structure GEMM. C[M][Nc] = A[M][K] * Bt[N][K]^T (bf16, f32 acc)
// 128x128 tile, BK=64, global_load_lds(16B) staging into linear LDS,
// 4 waves in 2x2, each owns a 64x64 output (4x4 fragments of 16x16x32).
// epilogue: v = acc*scale + bias[col]; write bf16 or fp32.
// ---------------------------------------------------------------------------
template <int WRITE_BF16>
__global__ __launch_bounds__(256) void gemm128(const short* __restrict__ A,
                                               const short* __restrict__ Bt,
                                               void* __restrict__ Cv,
                                               const float* __restrict__ bias,
                                               float scale, int M, int Nc, int K,
                                               long sA, long sB, long sC) {
  __shared__ short As[128 * 64];   // linear: gl_lds16 requires it
  __shared__ short Bs[128 * 64];
  A  += (long)blockIdx.z * sA;
  Bt += (long)blockIdx.z * sB;
  const int m0 = blockIdx.x * 128;
  const int n0 = blockIdx.y * 128;
  const int t = threadIdx.x;
  const int wave = t >> 6, lane = t & 63;
  const int lrow = lane & 15, lq = lane >> 4;
  const int wr = (wave >> 1) * 64, wc = (wave & 1) * 64;

  // staging: tile = 128 rows x 64 cols bf16 = 1024 x 16B chunks; 4/thread.
  const int srow = t >> 3;          // 0..31 (pass p adds 32 rows)
  const int scol = (t & 7) * 8;     // 0..56
  const short* Ag = A  + (long)(m0 + srow) * K + scol;
  const short* Bg = Bt + (long)(n0 + srow) * K + scol;
  short* Al = &As[srow * 64 + scol];
  short* Bl = &Bs[srow * 64 + scol];
  const long gstep = (long)32 * K;

  f32x4 acc[4][4] = {};
  for (int k0 = 0; k0 < K; k0 += 64) {
#pragma unroll
    for (int p = 0; p < 4; ++p) {
      gl_lds16(Ag + k0 + p * gstep, Al + p * 32 * 64);
      gl_lds16(Bg + k0 + p * gstep, Bl + p * 32 * 64);
    }
    __syncthreads();  // drains vmcnt -> LDS tiles ready
#pragma unroll
    for (int kk = 0; kk < 64; kk += 32) {
      bf16x8 a[4], b[4];
#pragma unroll
      for (int i = 0; i < 4; ++i) {
        a[i] = *(const bf16x8*)&As[(wr + i * 16 + lrow) * 64 + kk + lq * 8];
        b[i] = *(const bf16x8*)&Bs[(wc + i * 16 + lrow) * 64 + kk + lq * 8];
      }
#pragma unroll
      for (int m = 0; m < 4; ++m)
#pragma unroll
        for (int n = 0; n < 4; ++n)
          acc[m][n] = __builtin_amdgcn_mfma_f32_16x16x32_bf16(a[m], b[n], acc[m][n], 0, 0, 0);
    }
    __syncthreads();
  }

  const long cb = (long)blockIdx.z * sC;
#pragma unroll
  for (int m = 0; m < 4; ++m) {
#pragma unroll
    for (int r = 0; r < 4; ++r) {
      const long row = m0 + wr + m * 16 + lq * 4 + r;  // C/D: row = quad*4+reg
#pragma unroll
      for (int n = 0; n < 4; ++n) {
        const int col = n0 + wc + n * 16 + lrow;       // C/D: col = lane&15
        float v = acc[m][n][r] * scale;
        if (bias) v += bias[col];
        if (WRITE_BF16)
          ((short*)Cv)[cb + row * Nc + col] = f2bf(v);
        else
          ((float*)Cv)[cb + row * Nc + col] = v;
      }
    }
  }
}

// ---------------------------------------------------------------------------
// sigsoftmax: in-place on fp32 scores rows (already * 1/sqrt(d));
// att = softmax(sigmoid(s)); also write bf16 copy. sigmoid in (0,1) => no
// max-subtraction needed for a stable softmax.
// ---------------------------------------------------------------------------
__global__ __launch_bounds__(256) void sigsoftmax(float* __restrict__ att,
                                                  short* __restrict__ attbf) {
  const long row = blockIdx.x;
  float* p = att + row * NN;
  const int t = threadIdx.x;
  float2 v = *(float2*)&p[t * 2];
  const float s0 = 1.f / (1.f + __expf(-v.x));
  const float s1 = 1.f / (1.f + __expf(-v.y));
  const float e0 = __expf(s0), e1 = __expf(s1);
  float sum = e0 + e1;
#pragma unroll
  for (int o = 32; o > 0; o >>= 1) sum += __shfl_down(sum, o);
  __shared__ float wsum[4];
  if ((t & 63) == 0) wsum[t >> 6] = sum;
  __syncthreads();
  const float r = 1.f / (wsum[0] + wsum[1] + wsum[2] + wsum[3]);
  const float a0 = e0 * r, a1 = e1 * r;
  float2 o2; o2.x = a0; o2.y = a1;
  *(float2*)&p[t * 2] = o2;
  short pk[2] = {f2bf(a0), f2bf(a1)};
  *(unsigned int*)&attbf[row * NN + t * 2] = *(unsigned int*)pk;
}

// ---------------------------------------------------------------------------
// gemm_final: partials[split][32][512] = out1_bf[32][262144] * Wm[262144][512]
// Split-K over gridDim.x chunks, NO atomics: each split writes its own
// fp32 partial slab; reduce_out folds splits + bias.
// Wm staged via float4 loads, converted to bf16 + transposed into LDS.
// 4 waves: wave w owns 16 cols, both 16-row mtiles; BK=64 per iter.
// ---------------------------------------------------------------------------
__global__ __launch_bounds__(256) void gemm_final(const short* __restrict__ A,
                                                  const float* __restrict__ Wm,
                                                  float* __restrict__ part) {
  __shared__ short As[32 * 72];
  __shared__ short Bs[64 * 72];
  const int j0 = blockIdx.y * 64;
  const long KT = (long)NN * HH;          // 262144
  const long Kc = KT / gridDim.x;         // 2048 at 128 splits
  const long i0b = (long)blockIdx.x * Kc;
  const int t = threadIdx.x;
  const int wave = t >> 6, lane = t & 63;
  const int lrow = lane & 15, lq = lane >> 4;
  const int ar = t >> 3, ac = (t & 7) * 8;   // A stage: 32x64 bf16, 1 uint4/thread
  const int kr = t >> 4, jc = (t & 15) * 4;  // Wm stage: 64x64 f32, 4 float4/thread
  f32x4 acc[2] = {};
  for (long i0 = i0b; i0 < i0b + Kc; i0 += 64) {
    *(uint4*)&As[ar * 72 + ac] = *(const uint4*)&A[(long)ar * KT + i0 + ac];
#pragma unroll
    for (int p = 0; p < 4; ++p) {
      const float4 w = *(const float4*)&Wm[(i0 + kr + p * 16) * HH + j0 + jc];
      Bs[(jc + 0) * 72 + kr + p * 16] = f2bf(w.x);
      Bs[(jc + 1) * 72 + kr + p * 16] = f2bf(w.y);
      Bs[(jc + 2) * 72 + kr + p * 16] = f2bf(w.z);
      Bs[(jc + 3) * 72 + kr + p * 16] = f2bf(w.w);
    }
    __syncthreads();
#pragma unroll
    for (int kk = 0; kk < 64; kk += 32) {
      bf16x8 b  = *(const bf16x8*)&Bs[(wave * 16 + lrow) * 72 + kk + lq * 8];
      bf16x8 a0 = *(const bf16x8*)&As[lrow * 72 + kk + lq * 8];
      bf16x8 a1 = *(const bf16x8*)&As[(16 + lrow) * 72 + kk + lq * 8];
      acc[0] = __builtin_amdgcn_mfma_f32_16x16x32_bf16(a0, b, acc[0], 0, 0, 0);
      acc[1] = __builtin_amdgcn_mfma_f32_16x16x32_bf16(a1, b, acc[1], 0, 0, 0);
    }
    __syncthreads();
  }
  float* dst = part + (long)blockIdx.x * (BB * HH);
#pragma unroll
  for (int mt = 0; mt < 2; ++mt)
#pragma unroll
    for (int r = 0; r < 4; ++r) {
      const int row = mt * 16 + lq * 4 + r;
      const int col = j0 + wave * 16 + lrow;
      dst[(long)row * HH + col] = acc[mt][r];
    }
}

// out[idx] = bm[idx%512] + sum_p part[p][idx]   (128 splits, 8 MB read)
__global__ __launch_bounds__(256) void reduce_out(const float* __restrict__ part,
                                                  const float* __restrict__ bm,
                                                  float* __restrict__ out) {
  const int idx = blockIdx.x * 256 + threadIdx.x;
  float s0 = bm[idx & (HH - 1)], s1 = 0.f, s2 = 0.f, s3 = 0.f;
#pragma unroll 8
  for (int p = 0; p < 128; p += 4) {
    s0 += part[(long)(p + 0) * (BB * HH) + idx];
    s1 += part[(long)(p + 1) * (BB * HH) + idx];
    s2 += part[(long)(p + 2) * (BB * HH) + idx];
    s3 += part[(long)(p + 3) * (BB * HH) + idx];
  }
  out[idx] = (s0 + s1) + (s2 + s3);
}

extern "C" void kernel_launch(void* const* d_in, const int* in_sizes, int n_in,
                              void* d_out, int out_size, void* d_ws, size_t ws_size,
                              hipStream_t stream) {
  const float* x  = (const float*)d_in[0];
  const float* Wq = (const float*)d_in[1];
  const float* bq = (const float*)d_in[2];
  const float* Wk = (const float*)d_in[3];
  const float* bk = (const float*)d_in[4];
  const float* Wm = (const float*)d_in[5];
  const float* bm = (const float*)d_in[6];
  float* out = (float*)d_out;                 // [32*512]
  float* att = out + (long)BB * HH;           // [32*512*512] fp32

  char* ws = (char*)d_ws;
  const long SZ = (long)BB * NN * HH * sizeof(short);  // 16 MiB per buffer
  short* buf0 = (short*)ws;              // xbf, later reused as out1_bf
  short* buf1 = (short*)(ws + SZ);       // xT  [B][H][N]
  short* buf2 = (short*)(ws + 2 * SZ);   // q_bf, later reused as attn_bf
  short* buf3 = (short*)(ws + 3 * SZ);   // k_bf, later reused as partials
  short* wqt  = (short*)(ws + 4 * SZ);   // WqT bf16 [D][H]
  short* wkt  = wqt + (long)HH * HH;     // WkT bf16 [D][H]
  float* part = (float*)buf3;            // 128*32*512*4 = 8 MiB (k_bf dead by then)

  prep_x<<<dim3(HH / 32, NN / 32, BB), 256, 0, stream>>>(x, buf0, buf1);
  prep_w<<<dim3(HH / 32, HH / 32, 2), 256, 0, stream>>>(Wq, Wk, wqt, wkt);

  // q = x @ Wq + bq ; k = x @ Wk + bk   (M = B*N = 16384)
  gemm128<1><<<dim3(BB * NN / 128, HH / 128, 1), 256, 0, stream>>>(
      buf0, wqt, buf2, bq, 1.f, BB * NN, HH, HH, 0, 0, 0);
  gemm128<1><<<dim3(BB * NN / 128, HH / 128, 1), 256, 0, stream>>>(
      buf0, wkt, buf3, bk, 1.f, BB * NN, HH, HH, 0, 0, 0);

  // scores[b] = q[b] @ k[b]^T / sqrt(d)  -> fp32 into attention output region
  gemm128<0><<<dim3(NN / 128, NN / 128, BB), 256, 0, stream>>>(
      buf2, buf3, att, nullptr, QK_SCALE, NN, NN, HH,
      (long)NN * HH, (long)NN * HH, (long)NN * NN);

  // attention = softmax(sigmoid(scores)) in-place (fp32) + bf16 copy in buf2
  sigsoftmax<<<dim3(BB * NN), 256, 0, stream>>>(att, buf2);

  // out1[b] = attn[b] @ x[b]  (Bt = xT[b])  -> bf16 into buf0
  gemm128<1><<<dim3(NN / 128, HH / 128, BB), 256, 0, stream>>>(
      buf2, buf1, buf0, nullptr, 1.f, NN, HH, NN,
      (long)NN * NN, (long)HH * NN, (long)NN * HH);

  // out = out1_flat @ Wm + bm  (split-K partials, no atomics)
  gemm_final<<<dim3(128, HH / 64, 1), 256, 0, stream>>>(buf0, Wm, part);
  reduce_out<<<dim3(BB * HH / 256), 256, 0, stream>>>(part, bm, out);
}

// Round 3
// 834.172 us; speedup vs baseline: 1.0087x; 1.0087x over previous
//
#include <hip/hip_runtime.h>

#define BB 32
#define NN 512
#define HH 512
constexpr float QK_SCALE = 0.04419417382415922f; // 1/sqrt(512)

using bf16x8 = __attribute__((ext_vector_type(8))) short;
using f32x4  = __attribute__((ext_vector_type(4))) float;
typedef unsigned int u32;

// fp32 -> bf16 round-to-nearest-even (inputs are finite; no NaN path needed)
__device__ __forceinline__ short f2bf(float f) {
  unsigned int u = __float_as_uint(f);
  unsigned int r = (u + 0x7FFFu + ((u >> 16) & 1u)) >> 16;
  return (short)r;
}

// async global->LDS 16B copy. LDS dest must be wave-uniform base + lane*16,
// which all our staging index maps guarantee (linear in thread id).
__device__ __forceinline__ void gl_lds16(const short* g, short* l) {
  __builtin_amdgcn_global_load_lds(
      (const __attribute__((address_space(1))) u32*)g,
      (__attribute__((address_space(3))) u32*)l, 16, 0, 0);
}

// ---------------------------------------------------------------------------
// prep_all: one launch for both input preps.
//   blocks [0, 8192):   x fp32 [B][N][H] -> xbf bf16 (same layout), xT [B][H][N]
//   blocks [8192, 8704): Wq/Wk fp32 [H][D] -> Wqt/Wkt bf16 [D][H]
// ---------------------------------------------------------------------------
__global__ __launch_bounds__(256) void prep_all(const float* __restrict__ x,
                                                short* __restrict__ xbf,
                                                short* __restrict__ xT,
                                                const float* __restrict__ Wq,
                                                const float* __restrict__ Wk,
                                                short* __restrict__ Wqt,
                                                short* __restrict__ Wkt) {
  __shared__ float tile[32][33];
  const int bid = blockIdx.x;
  const int t = threadIdx.x;
  const int i = t >> 3;          // 0..31
  const int j4 = (t & 7) * 4;    // 0,4,...,28
  if (bid < 8192) {
    const int b = bid >> 8;
    const int n0 = ((bid >> 4) & 15) * 32, h0 = (bid & 15) * 32;
    const float4 v = *(const float4*)&x[((long)b * NN + n0 + i) * HH + h0 + j4];
    short o[4] = {f2bf(v.x), f2bf(v.y), f2bf(v.z), f2bf(v.w)};
    *(uint2*)&xbf[((long)b * NN + n0 + i) * HH + h0 + j4] = *(uint2*)o;
    tile[i][j4 + 0] = v.x; tile[i][j4 + 1] = v.y;
    tile[i][j4 + 2] = v.z; tile[i][j4 + 3] = v.w;
    __syncthreads();
    short p[4] = {f2bf(tile[j4 + 0][i]), f2bf(tile[j4 + 1][i]),
                  f2bf(tile[j4 + 2][i]), f2bf(tile[j4 + 3][i])};
    *(uint2*)&xT[((long)b * HH + h0 + i) * NN + n0 + j4] = *(uint2*)p;
  } else {
    const int id = bid - 8192;
    const float* W = (id >> 8) ? Wk : Wq;
    short* Wt = (id >> 8) ? Wkt : Wqt;
    const int h0 = ((id >> 4) & 15) * 32, d0 = (id & 15) * 32;
    const float4 v = *(const float4*)&W[(long)(h0 + i) * HH + d0 + j4];
    tile[i][j4 + 0] = v.x; tile[i][j4 + 1] = v.y;
    tile[i][j4 + 2] = v.z; tile[i][j4 + 3] = v.w;
    __syncthreads();
    short p[4] = {f2bf(tile[j4 + 0][i]), f2bf(tile[j4 + 1][i]),
                  f2bf(tile[j4 + 2][i]), f2bf(tile[j4 + 3][i])};
    *(uint2*)&Wt[(long)(d0 + i) * HH + h0 + j4] = *(uint2*)p;
  }
}

// ---------------------------------------------------------------------------
// gemm_qk: q = x@Wq + bq AND k = x@Wk + bk in one launch (blockIdx.z = 0/1).
// m97 structure: 128x128 tile, BK=64, global_load_lds(16B), 4 waves 2x2,
// each wave a 64x64 output (4x4 fragments of 16x16x32 bf16). Write bf16.
// Wt_pair: wqt at offset 0, wkt at HH*HH (contiguous in workspace).
// ---------------------------------------------------------------------------
__global__ __launch_bounds__(256) void gemm_qk(const short* __restrict__ A,
                                               const short* __restrict__ Wt_pair,
                                               short* __restrict__ Cq,
                                               short* __restrict__ Ck,
                                               const float* __restrict__ bq,
                                               const float* __restrict__ bk) {
  __shared__ short As[128 * 64];   // linear: gl_lds16 requires it
  __shared__ short Bs[128 * 64];
  const short* Bt = Wt_pair + (long)blockIdx.z * HH * HH;
  short* C = blockIdx.z ? Ck : Cq;
  const float* bias = blockIdx.z ? bk : bq;
  const int m0 = blockIdx.x * 128;
  const int n0 = blockIdx.y * 128;
  const int t = threadIdx.x;
  const int wave = t >> 6, lane = t & 63;
  const int lrow = lane & 15, lq = lane >> 4;
  const int wr = (wave >> 1) * 64, wc = (wave & 1) * 64;

  const int srow = t >> 3;          // 0..31 (pass p adds 32 rows)
  const int scol = (t & 7) * 8;     // 0..56
  const short* Ag = A + (long)(m0 + srow) * HH + scol;
  const short* Bg = Bt + (long)(n0 + srow) * HH + scol;
  short* Al = &As[srow * 64 + scol];
  short* Bl = &Bs[srow * 64 + scol];
  const long gstep = (long)32 * HH;

  f32x4 acc[4][4] = {};
  for (int k0 = 0; k0 < HH; k0 += 64) {
#pragma unroll
    for (int p = 0; p < 4; ++p) {
      gl_lds16(Ag + k0 + p * gstep, Al + p * 32 * 64);
      gl_lds16(Bg + k0 + p * gstep, Bl + p * 32 * 64);
    }
    __syncthreads();
#pragma unroll
    for (int kk = 0; kk < 64; kk += 32) {
      bf16x8 a[4], b[4];
#pragma unroll
      for (int i = 0; i < 4; ++i) {
        a[i] = *(const bf16x8*)&As[(wr + i * 16 + lrow) * 64 + kk + lq * 8];
        b[i] = *(const bf16x8*)&Bs[(wc + i * 16 + lrow) * 64 + kk + lq * 8];
      }
#pragma unroll
      for (int m = 0; m < 4; ++m)
#pragma unroll
        for (int n = 0; n < 4; ++n)
          acc[m][n] = __builtin_amdgcn_mfma_f32_16x16x32_bf16(a[m], b[n], acc[m][n], 0, 0, 0);
    }
    __syncthreads();
  }

#pragma unroll
  for (int m = 0; m < 4; ++m)
#pragma unroll
    for (int r = 0; r < 4; ++r) {
      const long row = m0 + wr + m * 16 + lq * 4 + r;  // C/D: row = quad*4+reg
#pragma unroll
      for (int n = 0; n < 4; ++n) {
        const int col = n0 + wc + n * 16 + lrow;       // C/D: col = lane&15
        C[row * HH + col] = f2bf(acc[m][n][r] + bias[col]);
      }
    }
}

// ---------------------------------------------------------------------------
// gemm_ssm: fused scores + sigmoid-softmax.
// Per block: 64 q-rows x ALL 512 k-cols of one batch, K(=d)=512, BK=32.
// LDS chunk map (dest &Xs[t*8], 16B per thread) => in a [rows][32] bf16 tile,
// thread t owns row t/4, cols (t%4)*8. Global source maps MUST match:
//   Q: q[b][r0 + t/4][(t%4)*8 + k0]
//   K: chunk p*256+t -> k[b][p*64 + t/4][(t%4)*8 + k0]
// Epilogue: s*=1/sqrt(d); att = softmax(sigmoid(s)) per row in-register
// (row spans the 16-lane C/D col-group x 32 n-tiles -> shfl_xor sum).
// Writes att fp32 + attbf bf16 IN PLACE over q (block reads only its own
// 64 rows, all reads drained by the final barrier before the writes).
// sigmoid in (0,1) => stable softmax without max-subtraction.
// ---------------------------------------------------------------------------
__global__ __launch_bounds__(256) void gemm_ssm(const short* q,   // no restrict:
                                                short* attbf,     // aliases q
                                                const short* __restrict__ k,
                                                float* __restrict__ att) {
  __shared__ short Qs[64 * 32];    // 4 KB
  __shared__ short Ks[512 * 32];   // 32 KB
  const int b = blockIdx.y;
  const int r0 = blockIdx.x * 64;
  const int t = threadIdx.x;
  const int wave = t >> 6, lane = t & 63;
  const int lrow = lane & 15, lq = lane >> 4;

  const short* qg = q + ((long)b * NN + r0 + (t >> 2)) * HH + (t & 3) * 8;
  short* ql = &Qs[t * 8];
  const short* kg = k + ((long)b * NN + (t >> 2)) * HH + (t & 3) * 8;
  short* kl = &Ks[t * 8];

  f32x4 acc[32];
#pragma unroll
  for (int i = 0; i < 32; ++i) acc[i] = (f32x4){0.f, 0.f, 0.f, 0.f};

  for (int k0 = 0; k0 < HH; k0 += 32) {
    gl_lds16(qg + k0, ql);
#pragma unroll
    for (int p = 0; p < 8; ++p)
      gl_lds16(kg + k0 + (long)p * 64 * HH, kl + p * 2048);
    __syncthreads();
    const bf16x8 a = *(const bf16x8*)&Qs[(wave * 16 + lrow) * 32 + lq * 8];
#pragma unroll
    for (int nt = 0; nt < 32; ++nt) {
      const bf16x8 bb = *(const bf16x8*)&Ks[(nt * 16 + lrow) * 32 + lq * 8];
      acc[nt] = __builtin_amdgcn_mfma_f32_16x16x32_bf16(a, bb, acc[nt], 0, 0, 0);
    }
    __syncthreads();
  }

  // epilogue: sigmoid -> exp -> row-sum -> normalize
  float rs[4] = {0.f, 0.f, 0.f, 0.f};
#pragma unroll
  for (int nt = 0; nt < 32; ++nt)
#pragma unroll
    for (int r = 0; r < 4; ++r) {
      const float s = acc[nt][r] * QK_SCALE;
      const float sg = 1.f / (1.f + __expf(-s));
      const float ev = __expf(sg);
      acc[nt][r] = ev;
      rs[r] += ev;
    }
#pragma unroll
  for (int r = 0; r < 4; ++r) {  // sum across the 16-lane col-group
    rs[r] += __shfl_xor(rs[r], 1);
    rs[r] += __shfl_xor(rs[r], 2);
    rs[r] += __shfl_xor(rs[r], 4);
    rs[r] += __shfl_xor(rs[r], 8);
    rs[r] = 1.f / rs[r];
  }
  const int row0 = r0 + wave * 16 + lq * 4;
#pragma unroll
  for (int nt = 0; nt < 32; ++nt)
#pragma unroll
    for (int r = 0; r < 4; ++r) {
      const float av = acc[nt][r] * rs[r];
      const long idx = ((long)b * NN + row0 + r) * NN + nt * 16 + lrow;
      att[idx] = av;
      attbf[idx] = f2bf(av);
    }
}

// ---------------------------------------------------------------------------
// gemm128: m97-structure batched GEMM, C[M][Nc] = A[M][K] * Bt[N][K]^T,
// bf16 out. Used for out1[b] = attn[b] @ x[b].
// ---------------------------------------------------------------------------
__global__ __launch_bounds__(256) void gemm128(const short* __restrict__ A,
                                               const short* __restrict__ Bt,
                                               short* __restrict__ C,
                                               int Nc, int K,
                                               long sA, long sB, long sC) {
  __shared__ short As[128 * 64];
  __shared__ short Bs[128 * 64];
  A += (long)blockIdx.z * sA;
  Bt += (long)blockIdx.z * sB;
  const int m0 = blockIdx.x * 128;
  const int n0 = blockIdx.y * 128;
  const int t = threadIdx.x;
  const int wave = t >> 6, lane = t & 63;
  const int lrow = lane & 15, lq = lane >> 4;
  const int wr = (wave >> 1) * 64, wc = (wave & 1) * 64;
  const int srow = t >> 3;
  const int scol = (t & 7) * 8;
  const short* Ag = A + (long)(m0 + srow) * K + scol;
  const short* Bg = Bt + (long)(n0 + srow) * K + scol;
  short* Al = &As[srow * 64 + scol];
  short* Bl = &Bs[srow * 64 + scol];
  const long gstep = (long)32 * K;

  f32x4 acc[4][4] = {};
  for (int k0 = 0; k0 < K; k0 += 64) {
#pragma unroll
    for (int p = 0; p < 4; ++p) {
      gl_lds16(Ag + k0 + p * gstep, Al + p * 32 * 64);
      gl_lds16(Bg + k0 + p * gstep, Bl + p * 32 * 64);
    }
    __syncthreads();
#pragma unroll
    for (int kk = 0; kk < 64; kk += 32) {
      bf16x8 a[4], b[4];
#pragma unroll
      for (int i = 0; i < 4; ++i) {
        a[i] = *(const bf16x8*)&As[(wr + i * 16 + lrow) * 64 + kk + lq * 8];
        b[i] = *(const bf16x8*)&Bs[(wc + i * 16 + lrow) * 64 + kk + lq * 8];
      }
#pragma unroll
      for (int m = 0; m < 4; ++m)
#pragma unroll
        for (int n = 0; n < 4; ++n)
          acc[m][n] = __builtin_amdgcn_mfma_f32_16x16x32_bf16(a[m], b[n], acc[m][n], 0, 0, 0);
    }
    __syncthreads();
  }

  const long cb = (long)blockIdx.z * sC;
#pragma unroll
  for (int m = 0; m < 4; ++m)
#pragma unroll
    for (int r = 0; r < 4; ++r) {
      const long row = m0 + wr + m * 16 + lq * 4 + r;
#pragma unroll
      for (int n = 0; n < 4; ++n) {
        const int col = n0 + wc + n * 16 + lrow;
        C[cb + row * Nc + col] = f2bf(acc[m][n][r]);
      }
    }
}

// ---------------------------------------------------------------------------
// gemm_final: partials[split][32][512] = out1_bf[32][262144] * Wm[262144][512]
// Split-K, no atomics. Wm staged via float4 loads, bf16-converted +
// transposed into LDS. 4 waves: wave w owns 16 cols, both 16-row mtiles.
// ---------------------------------------------------------------------------
__global__ __launch_bounds__(256) void gemm_final(const short* __restrict__ A,
                                                  const float* __restrict__ Wm,
                                                  float* __restrict__ part) {
  __shared__ short As[32 * 72];
  __shared__ short Bs[64 * 72];
  const int j0 = blockIdx.y * 64;
  const long KT = (long)NN * HH;          // 262144
  const long Kc = KT / gridDim.x;         // 2048 at 128 splits
  const long i0b = (long)blockIdx.x * Kc;
  const int t = threadIdx.x;
  const int wave = t >> 6, lane = t & 63;
  const int lrow = lane & 15, lq = lane >> 4;
  const int ar = t >> 3, ac = (t & 7) * 8;   // A stage: 32x64 bf16
  const int kr = t >> 4, jc = (t & 15) * 4;  // Wm stage: 64x64 f32
  f32x4 acc[2] = {};
  for (long i0 = i0b; i0 < i0b + Kc; i0 += 64) {
    *(uint4*)&As[ar * 72 + ac] = *(const uint4*)&A[(long)ar * KT + i0 + ac];
#pragma unroll
    for (int p = 0; p < 4; ++p) {
      const float4 w = *(const float4*)&Wm[(i0 + kr + p * 16) * HH + j0 + jc];
      Bs[(jc + 0) * 72 + kr + p * 16] = f2bf(w.x);
      Bs[(jc + 1) * 72 + kr + p * 16] = f2bf(w.y);
      Bs[(jc + 2) * 72 + kr + p * 16] = f2bf(w.z);
      Bs[(jc + 3) * 72 + kr + p * 16] = f2bf(w.w);
    }
    __syncthreads();
#pragma unroll
    for (int kk = 0; kk < 64; kk += 32) {
      bf16x8 b  = *(const bf16x8*)&Bs[(wave * 16 + lrow) * 72 + kk + lq * 8];
      bf16x8 a0 = *(const bf16x8*)&As[lrow * 72 + kk + lq * 8];
      bf16x8 a1 = *(const bf16x8*)&As[(16 + lrow) * 72 + kk + lq * 8];
      acc[0] = __builtin_amdgcn_mfma_f32_16x16x32_bf16(a0, b, acc[0], 0, 0, 0);
      acc[1] = __builtin_amdgcn_mfma_f32_16x16x32_bf16(a1, b, acc[1], 0, 0, 0);
    }
    __syncthreads();
  }
  float* dst = part + (long)blockIdx.x * (BB * HH);
#pragma unroll
  for (int mt = 0; mt < 2; ++mt)
#pragma unroll
    for (int r = 0; r < 4; ++r) {
      const int row = mt * 16 + lq * 4 + r;
      const int col = j0 + wave * 16 + lrow;
      dst[(long)row * HH + col] = acc[mt][r];
    }
}

// out[idx] = bm[idx%512] + sum_p part[p][idx]   (128 splits, 8 MB read)
__global__ __launch_bounds__(256) void reduce_out(const float* __restrict__ part,
                                                  const float* __restrict__ bm,
                                                  float* __restrict__ out) {
  const int idx = blockIdx.x * 256 + threadIdx.x;
  float s0 = bm[idx & (HH - 1)], s1 = 0.f, s2 = 0.f, s3 = 0.f;
#pragma unroll 8
  for (int p = 0; p < 128; p += 4) {
    s0 += part[(long)(p + 0) * (BB * HH) + idx];
    s1 += part[(long)(p + 1) * (BB * HH) + idx];
    s2 += part[(long)(p + 2) * (BB * HH) + idx];
    s3 += part[(long)(p + 3) * (BB * HH) + idx];
  }
  out[idx] = (s0 + s1) + (s2 + s3);
}

extern "C" void kernel_launch(void* const* d_in, const int* in_sizes, int n_in,
                              void* d_out, int out_size, void* d_ws, size_t ws_size,
                              hipStream_t stream) {
  const float* x  = (const float*)d_in[0];
  const float* Wq = (const float*)d_in[1];
  const float* bq = (const float*)d_in[2];
  const float* Wk = (const float*)d_in[3];
  const float* bk = (const float*)d_in[4];
  const float* Wm = (const float*)d_in[5];
  const float* bm = (const float*)d_in[6];
  float* out = (float*)d_out;                 // [32*512]
  float* att = out + (long)BB * HH;           // [32*512*512] fp32

  char* ws = (char*)d_ws;
  const long SZ = (long)BB * NN * HH * sizeof(short);  // 16 MiB per buffer
  short* buf0 = (short*)ws;              // xbf, later reused as out1_bf
  short* buf1 = (short*)(ws + SZ);       // xT  [B][H][N]
  short* buf2 = (short*)(ws + 2 * SZ);   // q_bf, overwritten in place by attbf
  short* buf3 = (short*)(ws + 3 * SZ);   // k_bf, later reused as partials
  short* wqt  = (short*)(ws + 4 * SZ);   // WqT bf16 [D][H]
  // wkt = wqt + HH*HH (contiguous pair, gemm_qk indexes by blockIdx.z)
  short* wkt  = wqt + (long)HH * HH;
  float* part = (float*)buf3;            // 128*32*512*4 = 8 MiB (k_bf dead)

  // 1. preps (x -> xbf,xT ; Wq/Wk -> wqt,wkt)
  prep_all<<<dim3(8192 + 512), 256, 0, stream>>>(x, buf0, buf1, Wq, Wk, wqt, wkt);

  // 2. q = x@Wq+bq, k = x@Wk+bk in one launch (z=0/1)
  gemm_qk<<<dim3(BB * NN / 128, HH / 128, 2), 256, 0, stream>>>(
      buf0, wqt, buf2, buf3, bq, bk);

  // 3. scores + sigmoid-softmax fused: att fp32 + attbf (in place over q)
  gemm_ssm<<<dim3(NN / 64, BB), 256, 0, stream>>>(buf2, buf2, buf3, att);

  // 4. out1[b] = attn[b] @ x[b]  -> bf16 into buf0
  gemm128<<<dim3(NN / 128, HH / 128, BB), 256, 0, stream>>>(
      buf2, buf1, buf0, HH, NN,
      (long)NN * NN, (long)HH * NN, (long)NN * HH);

  // 5-6. out = out1_flat @ Wm + bm  (split-K partials + reduce)
  gemm_final<<<dim3(128, HH / 64, 1), 256, 0, stream>>>(buf0, Wm, part);
  reduce_out<<<dim3(BB * HH / 256), 256, 0, stream>>>(part, bm, out);
}